// Round 1
// baseline (1231.931 us; speedup 1.0000x reference)
//
#include <hip/hip_runtime.h>

// AttentionEdgeModel: h = x_s[src]@Ws.T + x_t[tgt]@Wt.T + ea@We.T
//                     e = leakyrelu(h . w_attn); alpha = segment_softmax(e, src)
//                     out = rmsnorm(h*alpha) * norm_w
// Strategy: precompute node projections P_src/P_tgt and score scalars a_src/a_tgt,
// v_edge = We^T w_attn so the score pass never materializes h. Segment softmax via
// atomicMax on order-preserving uint encoding + atomicAdd denom. Final pass
// recomputes h (We rows in VGPRs, ea row via wave-private LDS broadcast).

#define N_SRC_N   50000
#define N_TGT_N   50000
#define N_EDGES_N 1000000
#define D_SRC_N   128
#define D_EDGE_N  64

__device__ __forceinline__ unsigned enc_f(float f) {
    unsigned u = __float_as_uint(f);
    return (u & 0x80000000u) ? ~u : (u | 0x80000000u);  // monotone float->uint
}
__device__ __forceinline__ float dec_f(unsigned u) {
    return (u & 0x80000000u) ? __uint_as_float(u & 0x7FFFFFFFu) : __uint_as_float(~u);
}

// ---- init segment-softmax state -------------------------------------------
__global__ void k_init(unsigned* __restrict__ m_enc, float* __restrict__ denom) {
    int i = blockIdx.x * blockDim.x + threadIdx.x;
    if (i < N_SRC_N) { m_enc[i] = 0u; denom[i] = 0.f; }  // 0 < enc(any finite float)
}

// ---- v_edge[k] = sum_j We[j][k] * w_attn[j] -------------------------------
__global__ void k_vedge(const float* __restrict__ W_edge, const float* __restrict__ w_attn,
                        float* __restrict__ v_edge) {
    int k = threadIdx.x;  // 64 threads
    float acc = 0.f;
    #pragma unroll
    for (int j = 0; j < 64; ++j) acc = fmaf(W_edge[j * 64 + k], w_attn[j], acc);
    v_edge[k] = acc;
}

// ---- node projections: P[n][j] = sum_k x[n][k]*W[j][k]; a[n] = P[n].w_attn -
// one wave per node row; lane j = output feature; W row j lives in VGPRs.
__global__ void __launch_bounds__(256) k_node(
    const float* __restrict__ x, const float* __restrict__ W,
    const float* __restrict__ w_attn, float* __restrict__ P, float* __restrict__ a,
    int nnodes) {
    int j   = threadIdx.x & 63;
    int wib = threadIdx.x >> 6;
    int gw  = blockIdx.x * 4 + wib;
    int nw  = gridDim.x * 4;
    float w[128];
    #pragma unroll
    for (int k4 = 0; k4 < 32; ++k4) {
        float4 t = *(const float4*)(W + j * 128 + k4 * 4);
        w[k4 * 4 + 0] = t.x; w[k4 * 4 + 1] = t.y; w[k4 * 4 + 2] = t.z; w[k4 * 4 + 3] = t.w;
    }
    float waj = w_attn[j];
    for (int row = gw; row < nnodes; row += nw) {
        const float* xr = x + (size_t)row * 128;
        float a0 = 0.f, a1 = 0.f, a2 = 0.f, a3 = 0.f;
        #pragma unroll
        for (int k4 = 0; k4 < 32; ++k4) {
            a0 = fmaf(xr[k4 * 4 + 0], w[k4 * 4 + 0], a0);
            a1 = fmaf(xr[k4 * 4 + 1], w[k4 * 4 + 1], a1);
            a2 = fmaf(xr[k4 * 4 + 2], w[k4 * 4 + 2], a2);
            a3 = fmaf(xr[k4 * 4 + 3], w[k4 * 4 + 3], a3);
        }
        float acc = (a0 + a1) + (a2 + a3);
        P[(size_t)row * 64 + j] = acc;
        float c = acc * waj;
        #pragma unroll
        for (int m = 1; m < 64; m <<= 1) c += __shfl_xor(c, m, 64);
        if (j == 0) a[row] = c;
    }
}

// ---- score pass: e = leaky(a_src[s]+a_tgt[t]+ea.v_edge); atomicMax m ------
// wave handles 4 edges/iter: lane = sub(2b)*16 + kq(4b); float4 per lane.
__global__ void __launch_bounds__(256) k_edge1(
    const float* __restrict__ ea, const int* __restrict__ ei,
    const float* __restrict__ a_src, const float* __restrict__ a_tgt,
    const float* __restrict__ v_edge, float* __restrict__ e_arr,
    unsigned* __restrict__ m_enc) {
    int lane = threadIdx.x & 63;
    int wib  = threadIdx.x >> 6;
    int gw   = blockIdx.x * 4 + wib;
    int nw   = gridDim.x * 4;
    int sub = lane >> 4, kq = lane & 15;
    float4 v4 = ((const float4*)v_edge)[kq];
    for (int base = gw * 4; base < N_EDGES_N; base += nw * 4) {
        int e = base + sub;
        float4 a4 = *(const float4*)(ea + (size_t)e * 64 + kq * 4);
        float p = fmaf(a4.x, v4.x, fmaf(a4.y, v4.y, fmaf(a4.z, v4.z, a4.w * v4.w)));
        p += __shfl_xor(p, 1, 64);
        p += __shfl_xor(p, 2, 64);
        p += __shfl_xor(p, 4, 64);
        p += __shfl_xor(p, 8, 64);
        if (kq == 0) {
            int s = ei[e], t = ei[N_EDGES_N + e];
            float val = p + a_src[s] + a_tgt[t];
            val = (val >= 0.f) ? val : 0.2f * val;
            e_arr[e] = val;
            atomicMax(m_enc + s, enc_f(val));
        }
    }
}

// ---- exp + denom accumulation ---------------------------------------------
__global__ void k_edge2(const float* __restrict__ e_arr, const int* __restrict__ ei,
                        const unsigned* __restrict__ m_enc, float* __restrict__ ex_arr,
                        float* __restrict__ denom) {
    int i = blockIdx.x * blockDim.x + threadIdx.x;
    if (i < N_EDGES_N) {
        int s = ei[i];
        float ex = __expf(e_arr[i] - dec_f(m_enc[s]));
        ex_arr[i] = ex;
        atomicAdd(denom + s, ex);
    }
}

// ---- final pass: h = P_src[s]+P_tgt[t]+ea@We.T; rmsnorm(h*alpha)*norm_w ---
// wave per edge; lane j = feature; We row j in VGPRs; ea row broadcast via LDS.
__global__ void __launch_bounds__(256) k_edge3(
    const float* __restrict__ ea, const int* __restrict__ ei,
    const float* __restrict__ P_src, const float* __restrict__ P_tgt,
    const float* __restrict__ W_edge, const float* __restrict__ norm_w,
    const float* __restrict__ ex_arr, const float* __restrict__ denom,
    float* __restrict__ out) {
    __shared__ __align__(16) float ea_s[4][64];
    int j   = threadIdx.x & 63;
    int wib = threadIdx.x >> 6;
    float w[64];
    #pragma unroll
    for (int k4 = 0; k4 < 16; ++k4) {
        float4 t = *(const float4*)(W_edge + j * 64 + k4 * 4);
        w[k4 * 4 + 0] = t.x; w[k4 * 4 + 1] = t.y; w[k4 * 4 + 2] = t.z; w[k4 * 4 + 3] = t.w;
    }
    float nwj = norm_w[j];
    // base depends only on blockIdx -> uniform iteration count per block (syncthreads-safe)
    for (int base = blockIdx.x * 4; base < N_EDGES_N; base += gridDim.x * 4) {
        int e = base + wib;  // N_EDGES % 4 == 0 -> always valid
        ea_s[wib][j] = ea[(size_t)e * 64 + j];
        __syncthreads();
        float a0 = 0.f, a1 = 0.f, a2 = 0.f, a3 = 0.f;
        #pragma unroll
        for (int k4 = 0; k4 < 16; ++k4) {
            float4 q = *(const float4*)&ea_s[wib][k4 * 4];
            a0 = fmaf(q.x, w[k4 * 4 + 0], a0);
            a1 = fmaf(q.y, w[k4 * 4 + 1], a1);
            a2 = fmaf(q.z, w[k4 * 4 + 2], a2);
            a3 = fmaf(q.w, w[k4 * 4 + 3], a3);
        }
        float acc = (a0 + a1) + (a2 + a3);
        int s = ei[e], t = ei[N_EDGES_N + e];
        float h = acc + P_src[(size_t)s * 64 + j] + P_tgt[(size_t)t * 64 + j];
        float alpha = ex_arr[e] / denom[s];
        float hh = h * alpha;
        float sq = hh * hh;
        #pragma unroll
        for (int m = 1; m < 64; m <<= 1) sq += __shfl_xor(sq, m, 64);
        float rms = rsqrtf(sq * (1.0f / 64.0f) + 1.1920929e-07f);
        out[(size_t)e * 64 + j] = hh * rms * nwj;
        __syncthreads();
    }
}

extern "C" void kernel_launch(void* const* d_in, const int* in_sizes, int n_in,
                              void* d_out, int out_size, void* d_ws, size_t ws_size,
                              hipStream_t stream) {
    const float* x_s    = (const float*)d_in[0];
    const float* x_t    = (const float*)d_in[1];
    const int*   ei     = (const int*)d_in[2];   // int32 per harness convention (JAX x64 off)
    const float* ea     = (const float*)d_in[3];
    // d_in[4] = x_u: unused by the reference
    const float* W_src  = (const float*)d_in[5];
    const float* W_tgt  = (const float*)d_in[6];
    const float* W_edge = (const float*)d_in[7];
    const float* w_attn = (const float*)d_in[8];
    const float* norm_w = (const float*)d_in[9];
    float* out = (float*)d_out;

    // workspace layout (floats): total 8,600,064 floats = 34.4 MB
    float* ws      = (float*)d_ws;
    float* P_src   = ws;                       // 50000*64
    float* P_tgt   = ws + 3200000;             // 50000*64
    float* a_src   = ws + 6400000;             // 50000
    float* a_tgt   = ws + 6450000;             // 50000
    float* v_edge  = ws + 6500000;             // 64
    unsigned* m_enc= (unsigned*)(ws + 6500064);// 50000
    float* denom   = ws + 6550064;             // 50000
    float* e_arr   = ws + 6600064;             // 1,000,000
    float* ex_arr  = ws + 7600064;             // 1,000,000

    k_init<<<(N_SRC_N + 255) / 256, 256, 0, stream>>>(m_enc, denom);
    k_vedge<<<1, 64, 0, stream>>>(W_edge, w_attn, v_edge);
    k_node<<<256, 256, 0, stream>>>(x_s, W_src, w_attn, P_src, a_src, N_SRC_N);
    k_node<<<256, 256, 0, stream>>>(x_t, W_tgt, w_attn, P_tgt, a_tgt, N_TGT_N);
    k_edge1<<<1024, 256, 0, stream>>>(ea, ei, a_src, a_tgt, v_edge, e_arr, m_enc);
    k_edge2<<<(N_EDGES_N + 255) / 256, 256, 0, stream>>>(e_arr, ei, m_enc, ex_arr, denom);
    k_edge3<<<2048, 256, 0, stream>>>(ea, ei, P_src, P_tgt, W_edge, norm_w, ex_arr, denom, out);
}